// Round 26
// baseline (253.112 us; speedup 1.0000x reference)
//
#include <hip/hip_runtime.h>

typedef __attribute__((ext_vector_type(8))) short short8;     // 8 bf16 — MFMA A/B frag
typedef __attribute__((ext_vector_type(4))) float f32x4;      // MFMA C/D frag
typedef __attribute__((ext_vector_type(4))) unsigned short u16x4;
typedef __attribute__((ext_vector_type(4))) float float4v;

#define MFMA(a, b, c) __builtin_amdgcn_mfma_f32_16x16x32_bf16(a, b, c, 0, 0, 0)
#define GLOAD_LDS16(gp, lp) __builtin_amdgcn_global_load_lds( \
    (const __attribute__((address_space(1))) void*)(gp),      \
    (__attribute__((address_space(3))) void*)(lp), 16, 0, 0)

__device__ __forceinline__ float bf2f(unsigned short u) {
    union { unsigned int i; float f; } v; v.i = ((unsigned int)u) << 16; return v.f;
}
__device__ __forceinline__ unsigned short f2bf(float f) {
    union { float f; unsigned int i; } v; v.f = f;
    unsigned int r = (v.i + 0x7FFFu + ((v.i >> 16) & 1u)) >> 16;
    return (unsigned short)r;
}
// pack two f32 -> u32 of 2 bf16 (lo = a, hi = b)
__device__ __forceinline__ unsigned int cvtpk(float a, float b) {
    unsigned int r;
    asm("v_cvt_pk_bf16_f32 %0, %1, %2" : "=v"(r) : "v"(a), "v"(b));
    return r;
}

// ---- fp32 -> bf16 ingest (vectorized) ----
__global__ __launch_bounds__(256)
void ingest(const float* __restrict__ src, unsigned short* __restrict__ dst, int n4)
{
    const int stride = gridDim.x * blockDim.x;
    for (int i = blockIdx.x * blockDim.x + threadIdx.x; i < n4; i += stride) {
        float4v v = ((const float4v*)src)[i];
        u16x4 o;
#pragma unroll
        for (int j = 0; j < 4; ++j) o[j] = f2bf(v[j]);
        ((u16x4*)dst)[i] = o;
    }
}

// ---- Projection GEMM (r17-verified, unchanged) ----
__global__ __launch_bounds__(256)
void proj_gemm(const unsigned short* __restrict__ X,
               const unsigned short* __restrict__ Wq, const unsigned short* __restrict__ Wk,
               const unsigned short* __restrict__ Wv, const unsigned short* __restrict__ Wr,
               unsigned short* __restrict__ Qo, unsigned short* __restrict__ Ko,
               unsigned short* __restrict__ Vo, unsigned short* __restrict__ Ro)
{
    constexpr int Kd = 1024, N = 1024;
    __shared__ unsigned short As[128 * 32];
    __shared__ unsigned short Bs[128 * 32];
    const int tid = threadIdx.x;
    const int wid = tid >> 6, lane = tid & 63;
    const int g = lane >> 4, lr = lane & 15;
    const int wsel = blockIdx.z;
    const unsigned short* W = (wsel == 0) ? Wq : (wsel == 1) ? Wk : (wsel == 2) ? Wv : Wr;
    unsigned short* O = (wsel == 0) ? Qo : (wsel == 1) ? Ko : (wsel == 2) ? Vo : Ro;
    const int rowBase = blockIdx.x * 128;
    const int colBase = blockIdx.y * 128;
    const int wm = wid >> 1, wn = wid & 1;

    f32x4 acc[4][4] = {};

    const int r0 = tid >> 2;
    const int c0 = (tid & 3) * 8;
    const unsigned short* ga0 = X + (size_t)(rowBase + r0) * Kd + c0;
    const unsigned short* ga1 = X + (size_t)(rowBase + 64 + r0) * Kd + c0;
    const unsigned short* gb0 = W + (size_t)(colBase + r0) * Kd + c0;
    const unsigned short* gb1 = W + (size_t)(colBase + 64 + r0) * Kd + c0;

    for (int kt = 0; kt < Kd; kt += 32) {
        if (kt) __syncthreads();
        GLOAD_LDS16(ga0 + kt, As + (size_t)tid * 8);
        GLOAD_LDS16(ga1 + kt, As + 2048 + (size_t)tid * 8);
        GLOAD_LDS16(gb0 + kt, Bs + (size_t)tid * 8);
        GLOAD_LDS16(gb1 + kt, Bs + 2048 + (size_t)tid * 8);
        asm volatile("s_waitcnt vmcnt(0)" ::: "memory");
        __syncthreads();
        short8 a[4], b[4];
#pragma unroll
        for (int mt = 0; mt < 4; ++mt)
            a[mt] = *reinterpret_cast<const short8*>(&As[(wm * 64 + mt * 16 + lr) * 32 + g * 8]);
#pragma unroll
        for (int nt = 0; nt < 4; ++nt)
            b[nt] = *reinterpret_cast<const short8*>(&Bs[(wn * 64 + nt * 16 + lr) * 32 + g * 8]);
#pragma unroll
        for (int mt = 0; mt < 4; ++mt)
#pragma unroll
            for (int nt = 0; nt < 4; ++nt)
                acc[mt][nt] = MFMA(a[mt], b[nt], acc[mt][nt]);
    }
#pragma unroll
    for (int mt = 0; mt < 4; ++mt)
#pragma unroll
        for (int nt = 0; nt < 4; ++nt)
#pragma unroll
            for (int r = 0; r < 4; ++r) {
                int row = rowBase + wm * 64 + mt * 16 + g * 4 + r;
                int col = colBase + wn * 64 + nt * 16 + lr;
                O[(size_t)row * N + col] = f2bf(acc[mt][nt][r]);
            }
}

// ---- MFMA flash attention: QB=128, XCD-colocated, dbuf K/V, fixed-max softmax,
//      SWAPPED QK^T with in-register P redistribution (no P-LDS roundtrip) ----
__global__ __launch_bounds__(512)
void attn_fwd(const unsigned short* __restrict__ Q, const unsigned short* __restrict__ Kb,
              const unsigned short* __restrict__ Vb, const int* __restrict__ mask,
              unsigned short* __restrict__ AO)
{
    constexpr int S = 2048, C = 1024, Dh = 64;
    constexpr float SCL = 0.125f * 1.44269504f;    // score scale in log2 domain
    constexpr float FM  = 16.0f;                   // fixed softmax max (log2 units)
    constexpr float MSK = -1.0e30f;                // masked: exp2 -> 0
    __shared__ unsigned short Kt[2][64 * 64];      // [buf][key][slot-swizzled d]
    __shared__ unsigned short Vt[2][64 * 64];      // [buf][d][slot-swizzled key]
    const int tid = threadIdx.x;
    const int w = tid >> 6, lane = tid & 63;
    const int g = lane >> 4, lr = lane & 15;
    const int lin = blockIdx.x;
    const int hb = lin & 63, qt = lin >> 6;
    const int h = hb >> 2, b = hb & 3;
    const int qbase = qt * 128;
    const int qrow = qbase + w * 16 + lr;

    const unsigned short* qptr = Q + (size_t)(b * S + qrow) * C + h * Dh;
    short8 qf[2];
    qf[0] = *reinterpret_cast<const short8*>(qptr + g * 8);
    qf[1] = *reinterpret_cast<const short8*>(qptr + 32 + g * 8);

    f32x4 o[4] = {};
    float ll = 0.f;                 // lane-partial P row-sum (q = lr)

    const unsigned short* kg = Kb + (size_t)(b * S) * C + h * Dh;
    const unsigned short* vg = Vb + (size_t)(b * S) * C + h * Dh;
    const int* mg = mask + b * S;

    // K staging: 512 chunks, one per thread (linear dest, pre-swizzled source)
    const int kk0 = tid >> 3;
    const int kd0 = ((tid & 7) ^ (kk0 & 7)) * 8;
    // V staging: one short8 per thread
    const int vkey = tid >> 3;
    const int vsd = (tid & 7) * 8;

    short8 vv;
    // ---- prologue: stage tile 0 into buf 0 ----
    GLOAD_LDS16(kg + (size_t)kk0 * C + kd0, &Kt[0][(size_t)tid * 8]);
    vv = *reinterpret_cast<const short8*>(vg + (size_t)vkey * C + vsd);
    asm volatile("s_waitcnt vmcnt(0)" ::: "memory");
    {
        const unsigned short* bb = (const unsigned short*)&vv;
#pragma unroll
        for (int j = 0; j < 8; ++j) {
            int d = vsd + j;
            int sw = (d & 7) ^ ((d >> 3) & 7);
            Vt[0][d * 64 + ((((vkey >> 3) ^ sw) << 3) | (vkey & 7))] = bb[j];
        }
    }
    __syncthreads();

    const int src0 = ((g & 1) << 5) + lr;   // = 2*(g&1)*16 + lr
    const int src1 = src0 + 16;
    const bool hiSel = (g >> 1) & 1;

    int cur = 0;
    for (int t = 0; t < S; t += 64) {
        const bool hasNext = (t + 64) < S;
        if (hasNext) {   // issue next tile's loads NOW; drain after compute
            const int tn = t + 64;
            GLOAD_LDS16(kg + (size_t)(tn + kk0) * C + kd0, &Kt[cur ^ 1][(size_t)tid * 8]);
            vv = *reinterpret_cast<const short8*>(vg + (size_t)(tn + vkey) * C + vsd);
        }
        // Swapped QK^T: D[key_local = g*4+r][q = lr]; kf is A-frag (same read addr)
        f32x4 s[4];
        __builtin_amdgcn_s_setprio(1);
#pragma unroll
        for (int nt = 0; nt < 4; ++nt) {
            int key = nt * 16 + lr;     // A-frag row index = lr
            f32x4 a = {};
#pragma unroll
            for (int c = 0; c < 2; ++c) {
                int dd = c * 32 + g * 8;
                short8 kf = *reinterpret_cast<const short8*>(
                    &Kt[cur][key * 64 + (((dd >> 3) ^ (key & 7)) << 3)]);
                a = MFMA(kf, qf[c], a);
            }
            s[nt] = a;
        }
        __builtin_amdgcn_s_setprio(0);
        // mask + exp2: lane holds P[key=16nt+4g+r][q=lr]; pack to bf16 pairs
        const int* mb = mg + t + 4 * g;
        unsigned int u0[4], u1[4];      // u0[nt] = keys (16nt+4g+0,1), u1[nt] = (+2,+3)
#pragma unroll
        for (int nt = 0; nt < 4; ++nt) {
            float pp[4];
#pragma unroll
            for (int r = 0; r < 4; ++r) {
                float madd = mb[16 * nt + r] ? -FM : MSK;
                pp[r] = __builtin_amdgcn_exp2f(s[nt][r] * SCL + madd);
                ll += pp[r];
            }
            u0[nt] = cvtpk(pp[0], pp[1]);
            u1[nt] = cvtpk(pp[2], pp[3]);
        }
        // redistribute: pf[hh] A-frag = P[q=lr][k=hh*32+g*8+j]
        union U8 { unsigned int wd[4]; short8 v; };
        U8 pf[2];
#pragma unroll
        for (int hh = 0; hh < 2; ++hh) {
            unsigned int a0 = __shfl(u0[2 * hh], src0, 64);
            unsigned int b0 = __shfl(u0[2 * hh + 1], src0, 64);
            unsigned int a1 = __shfl(u1[2 * hh], src0, 64);
            unsigned int b1 = __shfl(u1[2 * hh + 1], src0, 64);
            unsigned int a2 = __shfl(u0[2 * hh], src1, 64);
            unsigned int b2 = __shfl(u0[2 * hh + 1], src1, 64);
            unsigned int a3 = __shfl(u1[2 * hh], src1, 64);
            unsigned int b3 = __shfl(u1[2 * hh + 1], src1, 64);
            pf[hh].wd[0] = hiSel ? b0 : a0;
            pf[hh].wd[1] = hiSel ? b1 : a1;
            pf[hh].wd[2] = hiSel ? b2 : a2;
            pf[hh].wd[3] = hiSel ? b3 : a3;
        }
        // PV (reads unchanged)
        __builtin_amdgcn_s_setprio(1);
#pragma unroll
        for (int dt = 0; dt < 4; ++dt) {
            int d = dt * 16 + lr;
#pragma unroll
            for (int hh = 0; hh < 2; ++hh) {
                int kk = hh * 32 + g * 8;
                short8 vf = *reinterpret_cast<const short8*>(
                    &Vt[cur][d * 64 + ((((kk >> 3) ^ (d & 7) ^ ((d >> 3) & 7)) << 3))]);
                o[dt] = MFMA(pf[hh].v, vf, o[dt]);
            }
        }
        __builtin_amdgcn_s_setprio(0);
        // complete next-tile staging: drain DMA + scatter V regs
        if (hasNext) {
            asm volatile("s_waitcnt vmcnt(0)" ::: "memory");
            const unsigned short* bb = (const unsigned short*)&vv;
            unsigned short* Vn = Vt[cur ^ 1];
#pragma unroll
            for (int j = 0; j < 8; ++j) {
                int d = vsd + j;
                int sw = (d & 7) ^ ((d >> 3) & 7);
                Vn[d * 64 + ((((vkey >> 3) ^ sw) << 3) | (vkey & 7))] = bb[j];
            }
        }
        __syncthreads();
        cur ^= 1;
    }
    // finalize row-sums: reduce over the 4 g-groups, then redistribute to C-layout rows
    ll += __shfl_xor(ll, 16, 64);
    ll += __shfl_xor(ll, 32, 64);       // lane (g,lr): l for q = lr
    float lsel[4];
#pragma unroll
    for (int r = 0; r < 4; ++r)
        lsel[r] = __shfl(ll, g * 4 + r, 64);   // l for q = g*4+r (from lane lr=q)
#pragma unroll
    for (int dt = 0; dt < 4; ++dt)
#pragma unroll
        for (int r = 0; r < 4; ++r) {
            int row = qbase + w * 16 + g * 4 + r;
            int col = h * Dh + dt * 16 + lr;
            AO[(size_t)(b * S + row) * C + col] = f2bf(o[dt][r] / lsel[r]);
        }
}

// ---- Epilogue (r16-verified, unchanged) ----
__global__ __launch_bounds__(256)
void ln_ep(const unsigned short* __restrict__ AO, const unsigned short* __restrict__ R,
           const float* __restrict__ gamma, const float* __restrict__ beta,
           float* __restrict__ out)
{
    constexpr int C = 1024;
    const int row = blockIdx.x;
    const int tid = threadIdx.x;
    __shared__ float s1[256];
    __shared__ float s2[256];

    float v[4]; float sum = 0.f, ss = 0.f;
#pragma unroll
    for (int i = 0; i < 4; ++i) {
        int c = tid * 4 + i;
        float a = bf2f(AO[(size_t)row * C + c]);
        float r = bf2f(R[(size_t)row * C + c]);
        v[i] = fmaxf(0.f, a + r);
        sum += v[i]; ss += v[i] * v[i];
    }
    s1[tid] = sum; s2[tid] = ss;
    __syncthreads();
    for (int st = 128; st > 0; st >>= 1) {
        if (tid < st) { s1[tid] += s1[tid + st]; s2[tid] += s2[tid + st]; }
        __syncthreads();
    }
    float mu = s1[0] * (1.f / C);
    float var = s2[0] * (1.f / C) - mu * mu;
    float rstd = rsqrtf(var + 1e-5f);
    float4v g4 = *reinterpret_cast<const float4v*>(gamma + tid * 4);
    float4v b4 = *reinterpret_cast<const float4v*>(beta + tid * 4);
    float4v ov;
#pragma unroll
    for (int i = 0; i < 4; ++i)
        ov[i] = (v[i] - mu) * rstd * g4[i] + b4[i];
    *reinterpret_cast<float4v*>(out + (size_t)row * C + tid * 4) = ov;
}

extern "C" void kernel_launch(void* const* d_in, const int* in_sizes, int n_in,
                              void* d_out, int out_size, void* d_ws, size_t ws_size,
                              hipStream_t stream)
{
    const float* X = (const float*)d_in[0];
    const int* mask = (const int*)d_in[1];
    const float* Wq = (const float*)d_in[2];
    const float* Wk = (const float*)d_in[3];
    const float* Wv = (const float*)d_in[4];
    const float* Wr = (const float*)d_in[5];
    const float* Gm = (const float*)d_in[6];
    const float* Bt = (const float*)d_in[7];
    float* out = (float*)d_out;

    const size_t NE = (size_t)8192 * 1024;
    const size_t WE = (size_t)1024 * 1024;
    unsigned short* p = (unsigned short*)d_ws;
    unsigned short* Xb = p;   p += NE;
    unsigned short* Wqb = p;  p += WE;
    unsigned short* Wkb = p;  p += WE;
    unsigned short* Wvb = p;  p += WE;
    unsigned short* Wrb = p;  p += WE;
    unsigned short* Qb = p;   p += NE;
    unsigned short* Kb = p;   p += NE;
    unsigned short* Vb = p;   p += NE;
    unsigned short* Rb = p;   p += NE;
    unsigned short* AO = Xb;  // alias: X dead after proj_gemm

    ingest<<<dim3(2048), 256, 0, stream>>>(X, Xb, (int)(NE / 4));
    ingest<<<dim3(512), 256, 0, stream>>>(Wq, Wqb, (int)(WE / 4));
    ingest<<<dim3(512), 256, 0, stream>>>(Wk, Wkb, (int)(WE / 4));
    ingest<<<dim3(512), 256, 0, stream>>>(Wv, Wvb, (int)(WE / 4));
    ingest<<<dim3(512), 256, 0, stream>>>(Wr, Wrb, (int)(WE / 4));

    proj_gemm<<<dim3(64, 8, 4), 256, 0, stream>>>(Xb, Wqb, Wkb, Wvb, Wrb, Qb, Kb, Vb, Rb);
    attn_fwd<<<dim3(1024), 512, 0, stream>>>(Qb, Kb, Vb, mask, AO);
    ln_ep<<<dim3(8192), 256, 0, stream>>>(AO, Rb, Gm, Bt, out);
}

// Round 27
// 194.078 us; speedup vs baseline: 1.3042x; 1.3042x over previous
//
#include <hip/hip_runtime.h>

typedef __attribute__((ext_vector_type(8))) short short8;     // 8 bf16 — MFMA A/B frag
typedef __attribute__((ext_vector_type(4))) float f32x4;      // MFMA C/D frag
typedef __attribute__((ext_vector_type(4))) unsigned short u16x4;
typedef __attribute__((ext_vector_type(4))) float float4v;

#define MFMA(a, b, c) __builtin_amdgcn_mfma_f32_16x16x32_bf16(a, b, c, 0, 0, 0)
#define GLOAD_LDS16(gp, lp) __builtin_amdgcn_global_load_lds( \
    (const __attribute__((address_space(1))) void*)(gp),      \
    (__attribute__((address_space(3))) void*)(lp), 16, 0, 0)

__device__ __forceinline__ float bf2f(unsigned short u) {
    union { unsigned int i; float f; } v; v.i = ((unsigned int)u) << 16; return v.f;
}
__device__ __forceinline__ unsigned short f2bf(float f) {
    union { float f; unsigned int i; } v; v.f = f;
    unsigned int r = (v.i + 0x7FFFu + ((v.i >> 16) & 1u)) >> 16;
    return (unsigned short)r;
}
// cheap round-half-up bf16 (P tile only)
__device__ __forceinline__ unsigned short f2bfr(float f) {
    union { float f; unsigned int i; } v; v.f = f;
    return (unsigned short)((v.i + 0x8000u) >> 16);
}

// ---- mask compaction scan: rmap[b*S+s] = compact row (or -1), seff[b] = count ----
__global__ __launch_bounds__(256)
void mask_scan(const int* __restrict__ mask, int* __restrict__ rmap, int* __restrict__ seff)
{
    constexpr int S = 2048;
    const int b = blockIdx.x;
    const int tid = threadIdx.x;
    __shared__ int ps[256];
    const int* m = mask + b * S;
    int loc[8], s = 0;
#pragma unroll
    for (int j = 0; j < 8; ++j) { loc[j] = m[tid * 8 + j]; s += loc[j]; }
    ps[tid] = s;
    __syncthreads();
    for (int off = 1; off < 256; off <<= 1) {
        int v = (tid >= off) ? ps[tid - off] : 0;
        __syncthreads();
        ps[tid] += v;
        __syncthreads();
    }
    int run = (tid > 0) ? ps[tid - 1] : 0;   // exclusive prefix
#pragma unroll
    for (int j = 0; j < 8; ++j) {
        rmap[b * S + tid * 8 + j] = loc[j] ? (b * S + run) : -1;
        run += loc[j];
    }
    if (tid == 255) seff[b] = ps[255];
}

// ---- fp32 -> bf16 ingest (vectorized) ----
__global__ __launch_bounds__(256)
void ingest(const float* __restrict__ src, unsigned short* __restrict__ dst, int n4)
{
    const int stride = gridDim.x * blockDim.x;
    for (int i = blockIdx.x * blockDim.x + threadIdx.x; i < n4; i += stride) {
        float4v v = ((const float4v*)src)[i];
        u16x4 o;
#pragma unroll
        for (int j = 0; j < 4; ++j) o[j] = f2bf(v[j]);
        ((u16x4*)dst)[i] = o;
    }
}

// ---- Projection GEMM (r17-verified core; K/V stores routed through rmap) ----
__global__ __launch_bounds__(256)
void proj_gemm(const unsigned short* __restrict__ X,
               const unsigned short* __restrict__ Wq, const unsigned short* __restrict__ Wk,
               const unsigned short* __restrict__ Wv, const unsigned short* __restrict__ Wr,
               unsigned short* __restrict__ Qo, unsigned short* __restrict__ Ko,
               unsigned short* __restrict__ Vo, unsigned short* __restrict__ Ro,
               const int* __restrict__ rmap)
{
    constexpr int Kd = 1024, N = 1024;
    __shared__ unsigned short As[128 * 32];
    __shared__ unsigned short Bs[128 * 32];
    const int tid = threadIdx.x;
    const int wid = tid >> 6, lane = tid & 63;
    const int g = lane >> 4, lr = lane & 15;
    const int wsel = blockIdx.z;
    const unsigned short* W = (wsel == 0) ? Wq : (wsel == 1) ? Wk : (wsel == 2) ? Wv : Wr;
    unsigned short* O = (wsel == 0) ? Qo : (wsel == 1) ? Ko : (wsel == 2) ? Vo : Ro;
    const bool compact = (wsel == 1) || (wsel == 2);
    const int rowBase = blockIdx.x * 128;
    const int colBase = blockIdx.y * 128;
    const int wm = wid >> 1, wn = wid & 1;

    f32x4 acc[4][4] = {};

    const int r0 = tid >> 2;
    const int c0 = (tid & 3) * 8;
    const unsigned short* ga0 = X + (size_t)(rowBase + r0) * Kd + c0;
    const unsigned short* ga1 = X + (size_t)(rowBase + 64 + r0) * Kd + c0;
    const unsigned short* gb0 = W + (size_t)(colBase + r0) * Kd + c0;
    const unsigned short* gb1 = W + (size_t)(colBase + 64 + r0) * Kd + c0;

    for (int kt = 0; kt < Kd; kt += 32) {
        if (kt) __syncthreads();
        GLOAD_LDS16(ga0 + kt, As + (size_t)tid * 8);
        GLOAD_LDS16(ga1 + kt, As + 2048 + (size_t)tid * 8);
        GLOAD_LDS16(gb0 + kt, Bs + (size_t)tid * 8);
        GLOAD_LDS16(gb1 + kt, Bs + 2048 + (size_t)tid * 8);
        asm volatile("s_waitcnt vmcnt(0)" ::: "memory");
        __syncthreads();
        short8 a[4], b[4];
#pragma unroll
        for (int mt = 0; mt < 4; ++mt)
            a[mt] = *reinterpret_cast<const short8*>(&As[(wm * 64 + mt * 16 + lr) * 32 + g * 8]);
#pragma unroll
        for (int nt = 0; nt < 4; ++nt)
            b[nt] = *reinterpret_cast<const short8*>(&Bs[(wn * 64 + nt * 16 + lr) * 32 + g * 8]);
#pragma unroll
        for (int mt = 0; mt < 4; ++mt)
#pragma unroll
            for (int nt = 0; nt < 4; ++nt)
                acc[mt][nt] = MFMA(a[mt], b[nt], acc[mt][nt]);
    }
#pragma unroll
    for (int mt = 0; mt < 4; ++mt)
#pragma unroll
        for (int nt = 0; nt < 4; ++nt)
#pragma unroll
            for (int r = 0; r < 4; ++r) {
                int row = rowBase + wm * 64 + mt * 16 + g * 4 + r;
                int col = colBase + wn * 64 + nt * 16 + lr;
                if (compact) {
                    int orow = rmap[row];
                    if (orow >= 0) O[(size_t)orow * N + col] = f2bf(acc[mt][nt][r]);
                } else {
                    O[(size_t)row * N + col] = f2bf(acc[mt][nt][r]);
                }
            }
}

// ---- MFMA flash attention over COMPACTED K/V (r25 structure):
//      QB=128 (8 waves), XCD-colocated, dbuf K/V, fixed-max softmax, MFMA row-sum ----
__global__ __launch_bounds__(512)
void attn_fwd(const unsigned short* __restrict__ Q, const unsigned short* __restrict__ Kb,
              const unsigned short* __restrict__ Vb, const int* __restrict__ seff,
              unsigned short* __restrict__ AO)
{
    constexpr int S = 2048, C = 1024, Dh = 64;
    constexpr int PST = 64;
    constexpr float SCL = 0.125f * 1.44269504f;
    constexpr float FM  = 16.0f;
    constexpr float MSK = -1.0e30f;
    __shared__ unsigned short Kt[2][64 * 64];
    __shared__ unsigned short Vt[2][64 * 64];
    __shared__ unsigned short Pt[8][16 * PST];
    const int tid = threadIdx.x;
    const int w = tid >> 6, lane = tid & 63;
    const int g = lane >> 4, lr = lane & 15;
    const int lin = blockIdx.x;
    const int hb = lin & 63, qt = lin >> 6;
    const int h = hb >> 2, b = hb & 3;
    const int qbase = qt * 128;
    const int qrow = qbase + w * 16 + lr;

    const int Sb = seff[b];                  // uniform per block
    const int ntiles = (Sb + 63) >> 6;

    const unsigned short* qptr = Q + (size_t)(b * S + qrow) * C + h * Dh;
    short8 qf[2];
    qf[0] = *reinterpret_cast<const short8*>(qptr + g * 8);
    qf[1] = *reinterpret_cast<const short8*>(qptr + 32 + g * 8);

    short8 ones;
#pragma unroll
    for (int j = 0; j < 8; ++j) ones[j] = (short)0x3F80;

    f32x4 o[4] = {};
    f32x4 lacc = {};

    const unsigned short* kg = Kb + (size_t)(b * S) * C + h * Dh;
    const unsigned short* vg = Vb + (size_t)(b * S) * C + h * Dh;

    const int kk0 = tid >> 3;
    const int kd0 = ((tid & 7) ^ (kk0 & 7)) * 8;
    const int vkey = tid >> 3;
    const int vsd = (tid & 7) * 8;

    short8 vv;
    // ---- prologue: stage tile 0 ----
    GLOAD_LDS16(kg + (size_t)kk0 * C + kd0, &Kt[0][(size_t)tid * 8]);
    vv = *reinterpret_cast<const short8*>(vg + (size_t)vkey * C + vsd);
    asm volatile("s_waitcnt vmcnt(0)" ::: "memory");
    {
        const unsigned short* bb = (const unsigned short*)&vv;
#pragma unroll
        for (int j = 0; j < 8; ++j) {
            int d = vsd + j;
            int sw = (d & 7) ^ ((d >> 3) & 7);
            Vt[0][d * 64 + ((((vkey >> 3) ^ sw) << 3) | (vkey & 7))] = bb[j];
        }
    }
    __syncthreads();

    int cur = 0;
    for (int tt = 0; tt < ntiles; ++tt) {
        const int t = tt * 64;
        const bool hasNext = (tt + 1) < ntiles;
        if (hasNext) {
            const int tn = t + 64;
            GLOAD_LDS16(kg + (size_t)(tn + kk0) * C + kd0, &Kt[cur ^ 1][(size_t)tid * 8]);
            vv = *reinterpret_cast<const short8*>(vg + (size_t)(tn + vkey) * C + vsd);
        }
        // QK^T : C-layout [qrow=g*4+r][key=lr]
        f32x4 s[4];
        __builtin_amdgcn_s_setprio(1);
#pragma unroll
        for (int nt = 0; nt < 4; ++nt) {
            int key = nt * 16 + lr;
            f32x4 a = {};
#pragma unroll
            for (int c = 0; c < 2; ++c) {
                int dd = c * 32 + g * 8;
                short8 kf = *reinterpret_cast<const short8*>(
                    &Kt[cur][key * 64 + (((dd >> 3) ^ (key & 7)) << 3)]);
                a = MFMA(qf[c], kf, a);
            }
            s[nt] = a;
        }
        __builtin_amdgcn_s_setprio(0);
        // P = exp2(s*SCL + madd); tail keys (>= Sb) get MSK -> exactly 0
        float madd[4];
#pragma unroll
        for (int nt = 0; nt < 4; ++nt)
            madd[nt] = ((t + nt * 16 + lr) < Sb) ? -FM : MSK;
        unsigned short* Pw = Pt[w];
#pragma unroll
        for (int nt = 0; nt < 4; ++nt) {
            int k = nt * 16 + lr;
#pragma unroll
            for (int r = 0; r < 4; ++r) {
                float p = __builtin_amdgcn_exp2f(s[nt][r] * SCL + madd[nt]);
                int row = g * 4 + r;
                Pw[row * PST + ((((k >> 3) ^ (row & 7)) << 3) | (k & 7))] = f2bfr(p);
            }
        }
        asm volatile("s_waitcnt lgkmcnt(0)" ::: "memory");
        __builtin_amdgcn_sched_barrier(0);
        short8 pf[2];
#pragma unroll
        for (int hh = 0; hh < 2; ++hh) {
            int kk = hh * 32 + g * 8;
            pf[hh] = *reinterpret_cast<const short8*>(
                &Pw[lr * PST + (((kk >> 3) ^ (lr & 7)) << 3)]);
        }
        // PV + MFMA row-sum
        __builtin_amdgcn_s_setprio(1);
        lacc = MFMA(pf[0], ones, lacc);
        lacc = MFMA(pf[1], ones, lacc);
#pragma unroll
        for (int dt = 0; dt < 4; ++dt) {
            int d = dt * 16 + lr;
#pragma unroll
            for (int hh = 0; hh < 2; ++hh) {
                int kk = hh * 32 + g * 8;
                short8 vf = *reinterpret_cast<const short8*>(
                    &Vt[cur][d * 64 + ((((kk >> 3) ^ (d & 7) ^ ((d >> 3) & 7)) << 3))]);
                o[dt] = MFMA(pf[hh], vf, o[dt]);
            }
        }
        __builtin_amdgcn_s_setprio(0);
        if (hasNext) {
            asm volatile("s_waitcnt vmcnt(0)" ::: "memory");
            const unsigned short* bb = (const unsigned short*)&vv;
            unsigned short* Vn = Vt[cur ^ 1];
#pragma unroll
            for (int j = 0; j < 8; ++j) {
                int d = vsd + j;
                int sw = (d & 7) ^ ((d >> 3) & 7);
                Vn[d * 64 + ((((vkey >> 3) ^ sw) << 3) | (vkey & 7))] = bb[j];
            }
        }
        __syncthreads();
        cur ^= 1;
    }
#pragma unroll
    for (int dt = 0; dt < 4; ++dt)
#pragma unroll
        for (int r = 0; r < 4; ++r) {
            int row = qbase + w * 16 + g * 4 + r;
            int col = h * Dh + dt * 16 + lr;
            AO[(size_t)(b * S + row) * C + col] = f2bf(o[dt][r] / lacc[r]);
        }
}

// ---- Epilogue (r16-verified, unchanged) ----
__global__ __launch_bounds__(256)
void ln_ep(const unsigned short* __restrict__ AO, const unsigned short* __restrict__ R,
           const float* __restrict__ gamma, const float* __restrict__ beta,
           float* __restrict__ out)
{
    constexpr int C = 1024;
    const int row = blockIdx.x;
    const int tid = threadIdx.x;
    __shared__ float s1[256];
    __shared__ float s2[256];

    float v[4]; float sum = 0.f, ss = 0.f;
#pragma unroll
    for (int i = 0; i < 4; ++i) {
        int c = tid * 4 + i;
        float a = bf2f(AO[(size_t)row * C + c]);
        float r = bf2f(R[(size_t)row * C + c]);
        v[i] = fmaxf(0.f, a + r);
        sum += v[i]; ss += v[i] * v[i];
    }
    s1[tid] = sum; s2[tid] = ss;
    __syncthreads();
    for (int st = 128; st > 0; st >>= 1) {
        if (tid < st) { s1[tid] += s1[tid + st]; s2[tid] += s2[tid + st]; }
        __syncthreads();
    }
    float mu = s1[0] * (1.f / C);
    float var = s2[0] * (1.f / C) - mu * mu;
    float rstd = rsqrtf(var + 1e-5f);
    float4v g4 = *reinterpret_cast<const float4v*>(gamma + tid * 4);
    float4v b4 = *reinterpret_cast<const float4v*>(beta + tid * 4);
    float4v ov;
#pragma unroll
    for (int i = 0; i < 4; ++i)
        ov[i] = (v[i] - mu) * rstd * g4[i] + b4[i];
    *reinterpret_cast<float4v*>(out + (size_t)row * C + tid * 4) = ov;
}

extern "C" void kernel_launch(void* const* d_in, const int* in_sizes, int n_in,
                              void* d_out, int out_size, void* d_ws, size_t ws_size,
                              hipStream_t stream)
{
    const float* X = (const float*)d_in[0];
    const int* mask = (const int*)d_in[1];
    const float* Wq = (const float*)d_in[2];
    const float* Wk = (const float*)d_in[3];
    const float* Wv = (const float*)d_in[4];
    const float* Wr = (const float*)d_in[5];
    const float* Gm = (const float*)d_in[6];
    const float* Bt = (const float*)d_in[7];
    float* out = (float*)d_out;

    const size_t NE = (size_t)8192 * 1024;
    const size_t WE = (size_t)1024 * 1024;
    unsigned short* p = (unsigned short*)d_ws;
    unsigned short* Xb = p;   p += NE;
    unsigned short* Wqb = p;  p += WE;
    unsigned short* Wkb = p;  p += WE;
    unsigned short* Wvb = p;  p += WE;
    unsigned short* Wrb = p;  p += WE;
    unsigned short* Qb = p;   p += NE;
    unsigned short* Kb = p;   p += NE;
    unsigned short* Vb = p;   p += NE;
    unsigned short* Rb = p;   p += NE;
    int* rmap = (int*)p;      p += 8192 * 2;   // 8192 ints
    int* seff = (int*)p;      p += 8;          // 4 ints
    unsigned short* AO = Xb;  // alias: X dead after proj_gemm

    mask_scan<<<dim3(4), 256, 0, stream>>>(mask, rmap, seff);
    ingest<<<dim3(2048), 256, 0, stream>>>(X, Xb, (int)(NE / 4));
    ingest<<<dim3(512), 256, 0, stream>>>(Wq, Wqb, (int)(WE / 4));
    ingest<<<dim3(512), 256, 0, stream>>>(Wk, Wkb, (int)(WE / 4));
    ingest<<<dim3(512), 256, 0, stream>>>(Wv, Wvb, (int)(WE / 4));
    ingest<<<dim3(512), 256, 0, stream>>>(Wr, Wrb, (int)(WE / 4));

    proj_gemm<<<dim3(64, 8, 4), 256, 0, stream>>>(Xb, Wqb, Wkb, Wvb, Wrb,
                                                  Qb, Kb, Vb, Rb, rmap);
    attn_fwd<<<dim3(1024), 512, 0, stream>>>(Qb, Kb, Vb, seff, AO);
    ln_ep<<<dim3(8192), 256, 0, stream>>>(AO, Rb, Gm, Bt, out);
}

// Round 28
// 177.244 us; speedup vs baseline: 1.4280x; 1.0950x over previous
//
#include <hip/hip_runtime.h>

typedef __attribute__((ext_vector_type(8))) short short8;     // 8 bf16 — MFMA A/B frag
typedef __attribute__((ext_vector_type(4))) float f32x4;      // MFMA C/D frag
typedef __attribute__((ext_vector_type(4))) unsigned short u16x4;
typedef __attribute__((ext_vector_type(4))) float float4v;

#define MFMA(a, b, c) __builtin_amdgcn_mfma_f32_16x16x32_bf16(a, b, c, 0, 0, 0)
#define GLOAD_LDS16(gp, lp) __builtin_amdgcn_global_load_lds( \
    (const __attribute__((address_space(1))) void*)(gp),      \
    (__attribute__((address_space(3))) void*)(lp), 16, 0, 0)

__device__ __forceinline__ float bf2f(unsigned short u) {
    union { unsigned int i; float f; } v; v.i = ((unsigned int)u) << 16; return v.f;
}
__device__ __forceinline__ unsigned short f2bf(float f) {
    union { float f; unsigned int i; } v; v.f = f;
    unsigned int r = (v.i + 0x7FFFu + ((v.i >> 16) & 1u)) >> 16;
    return (unsigned short)r;
}
// cheap round-half-up bf16 (P tile only)
__device__ __forceinline__ unsigned short f2bfr(float f) {
    union { float f; unsigned int i; } v; v.f = f;
    return (unsigned short)((v.i + 0x8000u) >> 16);
}

// ---- mask compaction: kidx[b*S+j] = source row of j-th unmasked key (tail -> b*S); seff[b] ----
__global__ __launch_bounds__(256)
void mask_scan(const int* __restrict__ mask, int* __restrict__ kidx, int* __restrict__ seff)
{
    constexpr int S = 2048;
    const int b = blockIdx.x;
    const int tid = threadIdx.x;
    __shared__ int ps[256];
    const int* m = mask + b * S;
    int loc[8], s = 0;
#pragma unroll
    for (int j = 0; j < 8; ++j) { loc[j] = m[tid * 8 + j]; s += loc[j]; }
#pragma unroll
    for (int j = 0; j < 8; ++j) kidx[b * S + tid * 8 + j] = b * S;   // safe default
    ps[tid] = s;
    __syncthreads();
    for (int off = 1; off < 256; off <<= 1) {
        int v = (tid >= off) ? ps[tid - off] : 0;
        __syncthreads();
        ps[tid] += v;
        __syncthreads();
    }
    int run = (tid > 0) ? ps[tid - 1] : 0;   // exclusive prefix
#pragma unroll
    for (int j = 0; j < 8; ++j) {
        if (loc[j]) kidx[b * S + run] = b * S + tid * 8 + j;
        run += loc[j];
    }
    if (tid == 255) seff[b] = ps[255];
}

// ---- fp32 -> bf16 ingest (vectorized) ----
__global__ __launch_bounds__(256)
void ingest(const float* __restrict__ src, unsigned short* __restrict__ dst, int n4)
{
    const int stride = gridDim.x * blockDim.x;
    for (int i = blockIdx.x * blockDim.x + threadIdx.x; i < n4; i += stride) {
        float4v v = ((const float4v*)src)[i];
        u16x4 o;
#pragma unroll
        for (int j = 0; j < 4; ++j) o[j] = f2bf(v[j]);
        ((u16x4*)dst)[i] = o;
    }
}

// ---- Projection GEMM (m97 core). z=0:Q  z=1:K(compact)  z=2:V(compact)  z=3:R ----
// Compact z's compute only unmasked rows via kidx indirection; early-exit past seff.
__global__ __launch_bounds__(256)
void proj_gemm(const unsigned short* __restrict__ X,
               const unsigned short* __restrict__ Wq, const unsigned short* __restrict__ Wk,
               const unsigned short* __restrict__ Wv, const unsigned short* __restrict__ Wr,
               unsigned short* __restrict__ Qo, unsigned short* __restrict__ Ko,
               unsigned short* __restrict__ Vo, unsigned short* __restrict__ Ro,
               const int* __restrict__ kidx, const int* __restrict__ seff)
{
    constexpr int Kd = 1024, N = 1024;
    __shared__ unsigned short As[128 * 32];
    __shared__ unsigned short Bs[128 * 32];
    const int tid = threadIdx.x;
    const int wid = tid >> 6, lane = tid & 63;
    const int g = lane >> 4, lr = lane & 15;
    const int wsel = blockIdx.z;
    const bool compact = (wsel == 1) || (wsel == 2);
    int rowBase;
    if (compact) {
        int bx = blockIdx.x;
        int b = bx / 17, xt = bx - b * 17;
        if (xt * 128 >= seff[b]) return;
        rowBase = b * 2048 + xt * 128;
    } else {
        if (blockIdx.x >= 64) return;
        rowBase = blockIdx.x * 128;
    }
    const unsigned short* W = (wsel == 0) ? Wq : (wsel == 1) ? Wk : (wsel == 2) ? Wv : Wr;
    unsigned short* O = (wsel == 0) ? Qo : (wsel == 1) ? Ko : (wsel == 2) ? Vo : Ro;
    const int colBase = blockIdx.y * 128;
    const int wm = wid >> 1, wn = wid & 1;

    f32x4 acc[4][4] = {};

    const int r0 = tid >> 2;
    const int c0 = (tid & 3) * 8;
    const int sA0 = compact ? kidx[rowBase + r0] : rowBase + r0;
    const int sA1 = compact ? kidx[rowBase + 64 + r0] : rowBase + 64 + r0;
    const unsigned short* ga0 = X + (size_t)sA0 * Kd + c0;
    const unsigned short* ga1 = X + (size_t)sA1 * Kd + c0;
    const unsigned short* gb0 = W + (size_t)(colBase + r0) * Kd + c0;
    const unsigned short* gb1 = W + (size_t)(colBase + 64 + r0) * Kd + c0;

    for (int kt = 0; kt < Kd; kt += 32) {
        if (kt) __syncthreads();
        GLOAD_LDS16(ga0 + kt, As + (size_t)tid * 8);
        GLOAD_LDS16(ga1 + kt, As + 2048 + (size_t)tid * 8);
        GLOAD_LDS16(gb0 + kt, Bs + (size_t)tid * 8);
        GLOAD_LDS16(gb1 + kt, Bs + 2048 + (size_t)tid * 8);
        asm volatile("s_waitcnt vmcnt(0)" ::: "memory");
        __syncthreads();
        short8 a[4], b[4];
#pragma unroll
        for (int mt = 0; mt < 4; ++mt)
            a[mt] = *reinterpret_cast<const short8*>(&As[(wm * 64 + mt * 16 + lr) * 32 + g * 8]);
#pragma unroll
        for (int nt = 0; nt < 4; ++nt)
            b[nt] = *reinterpret_cast<const short8*>(&Bs[(wn * 64 + nt * 16 + lr) * 32 + g * 8]);
#pragma unroll
        for (int mt = 0; mt < 4; ++mt)
#pragma unroll
            for (int nt = 0; nt < 4; ++nt)
                acc[mt][nt] = MFMA(a[mt], b[nt], acc[mt][nt]);
    }
#pragma unroll
    for (int mt = 0; mt < 4; ++mt)
#pragma unroll
        for (int nt = 0; nt < 4; ++nt)
#pragma unroll
            for (int r = 0; r < 4; ++r) {
                int row = rowBase + wm * 64 + mt * 16 + g * 4 + r;
                int col = colBase + wn * 64 + nt * 16 + lr;
                O[(size_t)row * N + col] = f2bf(acc[mt][nt][r]);
            }
}

// ---- MFMA flash attention over COMPACTED K/V (r27-verified, unchanged) ----
__global__ __launch_bounds__(512)
void attn_fwd(const unsigned short* __restrict__ Q, const unsigned short* __restrict__ Kb,
              const unsigned short* __restrict__ Vb, const int* __restrict__ seff,
              unsigned short* __restrict__ AO)
{
    constexpr int S = 2048, C = 1024, Dh = 64;
    constexpr int PST = 64;
    constexpr float SCL = 0.125f * 1.44269504f;
    constexpr float FM  = 16.0f;
    constexpr float MSK = -1.0e30f;
    __shared__ unsigned short Kt[2][64 * 64];
    __shared__ unsigned short Vt[2][64 * 64];
    __shared__ unsigned short Pt[8][16 * PST];
    const int tid = threadIdx.x;
    const int w = tid >> 6, lane = tid & 63;
    const int g = lane >> 4, lr = lane & 15;
    const int lin = blockIdx.x;
    const int hb = lin & 63, qt = lin >> 6;
    const int h = hb >> 2, b = hb & 3;
    const int qbase = qt * 128;
    const int qrow = qbase + w * 16 + lr;

    const int Sb = seff[b];
    const int ntiles = (Sb + 63) >> 6;

    const unsigned short* qptr = Q + (size_t)(b * S + qrow) * C + h * Dh;
    short8 qf[2];
    qf[0] = *reinterpret_cast<const short8*>(qptr + g * 8);
    qf[1] = *reinterpret_cast<const short8*>(qptr + 32 + g * 8);

    short8 ones;
#pragma unroll
    for (int j = 0; j < 8; ++j) ones[j] = (short)0x3F80;

    f32x4 o[4] = {};
    f32x4 lacc = {};

    const unsigned short* kg = Kb + (size_t)(b * S) * C + h * Dh;
    const unsigned short* vg = Vb + (size_t)(b * S) * C + h * Dh;

    const int kk0 = tid >> 3;
    const int kd0 = ((tid & 7) ^ (kk0 & 7)) * 8;
    const int vkey = tid >> 3;
    const int vsd = (tid & 7) * 8;

    short8 vv;
    GLOAD_LDS16(kg + (size_t)kk0 * C + kd0, &Kt[0][(size_t)tid * 8]);
    vv = *reinterpret_cast<const short8*>(vg + (size_t)vkey * C + vsd);
    asm volatile("s_waitcnt vmcnt(0)" ::: "memory");
    {
        const unsigned short* bb = (const unsigned short*)&vv;
#pragma unroll
        for (int j = 0; j < 8; ++j) {
            int d = vsd + j;
            int sw = (d & 7) ^ ((d >> 3) & 7);
            Vt[0][d * 64 + ((((vkey >> 3) ^ sw) << 3) | (vkey & 7))] = bb[j];
        }
    }
    __syncthreads();

    int cur = 0;
    for (int tt = 0; tt < ntiles; ++tt) {
        const int t = tt * 64;
        const bool hasNext = (tt + 1) < ntiles;
        if (hasNext) {
            const int tn = t + 64;
            GLOAD_LDS16(kg + (size_t)(tn + kk0) * C + kd0, &Kt[cur ^ 1][(size_t)tid * 8]);
            vv = *reinterpret_cast<const short8*>(vg + (size_t)(tn + vkey) * C + vsd);
        }
        f32x4 s[4];
        __builtin_amdgcn_s_setprio(1);
#pragma unroll
        for (int nt = 0; nt < 4; ++nt) {
            int key = nt * 16 + lr;
            f32x4 a = {};
#pragma unroll
            for (int c = 0; c < 2; ++c) {
                int dd = c * 32 + g * 8;
                short8 kf = *reinterpret_cast<const short8*>(
                    &Kt[cur][key * 64 + (((dd >> 3) ^ (key & 7)) << 3)]);
                a = MFMA(qf[c], kf, a);
            }
            s[nt] = a;
        }
        __builtin_amdgcn_s_setprio(0);
        float madd[4];
#pragma unroll
        for (int nt = 0; nt < 4; ++nt)
            madd[nt] = ((t + nt * 16 + lr) < Sb) ? -FM : MSK;
        unsigned short* Pw = Pt[w];
#pragma unroll
        for (int nt = 0; nt < 4; ++nt) {
            int k = nt * 16 + lr;
#pragma unroll
            for (int r = 0; r < 4; ++r) {
                float p = __builtin_amdgcn_exp2f(s[nt][r] * SCL + madd[nt]);
                int row = g * 4 + r;
                Pw[row * PST + ((((k >> 3) ^ (row & 7)) << 3) | (k & 7))] = f2bfr(p);
            }
        }
        asm volatile("s_waitcnt lgkmcnt(0)" ::: "memory");
        __builtin_amdgcn_sched_barrier(0);
        short8 pf[2];
#pragma unroll
        for (int hh = 0; hh < 2; ++hh) {
            int kk = hh * 32 + g * 8;
            pf[hh] = *reinterpret_cast<const short8*>(
                &Pw[lr * PST + (((kk >> 3) ^ (lr & 7)) << 3)]);
        }
        __builtin_amdgcn_s_setprio(1);
        lacc = MFMA(pf[0], ones, lacc);
        lacc = MFMA(pf[1], ones, lacc);
#pragma unroll
        for (int dt = 0; dt < 4; ++dt) {
            int d = dt * 16 + lr;
#pragma unroll
            for (int hh = 0; hh < 2; ++hh) {
                int kk = hh * 32 + g * 8;
                short8 vf = *reinterpret_cast<const short8*>(
                    &Vt[cur][d * 64 + ((((kk >> 3) ^ (d & 7) ^ ((d >> 3) & 7)) << 3))]);
                o[dt] = MFMA(pf[hh], vf, o[dt]);
            }
        }
        __builtin_amdgcn_s_setprio(0);
        if (hasNext) {
            asm volatile("s_waitcnt vmcnt(0)" ::: "memory");
            const unsigned short* bb = (const unsigned short*)&vv;
            unsigned short* Vn = Vt[cur ^ 1];
#pragma unroll
            for (int j = 0; j < 8; ++j) {
                int d = vsd + j;
                int sw = (d & 7) ^ ((d >> 3) & 7);
                Vn[d * 64 + ((((vkey >> 3) ^ sw) << 3) | (vkey & 7))] = bb[j];
            }
        }
        __syncthreads();
        cur ^= 1;
    }
#pragma unroll
    for (int dt = 0; dt < 4; ++dt)
#pragma unroll
        for (int r = 0; r < 4; ++r) {
            int row = qbase + w * 16 + g * 4 + r;
            int col = h * Dh + dt * 16 + lr;
            AO[(size_t)(b * S + row) * C + col] = f2bf(o[dt][r] / lacc[r]);
        }
}

// ---- Epilogue (r16-verified, unchanged) ----
__global__ __launch_bounds__(256)
void ln_ep(const unsigned short* __restrict__ AO, const unsigned short* __restrict__ R,
           const float* __restrict__ gamma, const float* __restrict__ beta,
           float* __restrict__ out)
{
    constexpr int C = 1024;
    const int row = blockIdx.x;
    const int tid = threadIdx.x;
    __shared__ float s1[256];
    __shared__ float s2[256];

    float v[4]; float sum = 0.f, ss = 0.f;
#pragma unroll
    for (int i = 0; i < 4; ++i) {
        int c = tid * 4 + i;
        float a = bf2f(AO[(size_t)row * C + c]);
        float r = bf2f(R[(size_t)row * C + c]);
        v[i] = fmaxf(0.f, a + r);
        sum += v[i]; ss += v[i] * v[i];
    }
    s1[tid] = sum; s2[tid] = ss;
    __syncthreads();
    for (int st = 128; st > 0; st >>= 1) {
        if (tid < st) { s1[tid] += s1[tid + st]; s2[tid] += s2[tid + st]; }
        __syncthreads();
    }
    float mu = s1[0] * (1.f / C);
    float var = s2[0] * (1.f / C) - mu * mu;
    float rstd = rsqrtf(var + 1e-5f);
    float4v g4 = *reinterpret_cast<const float4v*>(gamma + tid * 4);
    float4v b4 = *reinterpret_cast<const float4v*>(beta + tid * 4);
    float4v ov;
#pragma unroll
    for (int i = 0; i < 4; ++i)
        ov[i] = (v[i] - mu) * rstd * g4[i] + b4[i];
    *reinterpret_cast<float4v*>(out + (size_t)row * C + tid * 4) = ov;
}

extern "C" void kernel_launch(void* const* d_in, const int* in_sizes, int n_in,
                              void* d_out, int out_size, void* d_ws, size_t ws_size,
                              hipStream_t stream)
{
    const float* X = (const float*)d_in[0];
    const int* mask = (const int*)d_in[1];
    const float* Wq = (const float*)d_in[2];
    const float* Wk = (const float*)d_in[3];
    const float* Wv = (const float*)d_in[4];
    const float* Wr = (const float*)d_in[5];
    const float* Gm = (const float*)d_in[6];
    const float* Bt = (const float*)d_in[7];
    float* out = (float*)d_out;

    const size_t NE = (size_t)8192 * 1024;
    const size_t WE = (size_t)1024 * 1024;
    unsigned short* p = (unsigned short*)d_ws;
    unsigned short* Xb = p;   p += NE;
    unsigned short* Wqb = p;  p += WE;
    unsigned short* Wkb = p;  p += WE;
    unsigned short* Wvb = p;  p += WE;
    unsigned short* Wrb = p;  p += WE;
    unsigned short* Qb = p;   p += NE;
    unsigned short* Kb = p;   p += NE;
    unsigned short* Vb = p;   p += NE;
    unsigned short* Rb = p;   p += NE;
    int* kidx = (int*)p;      p += 8192 * 2;   // 8192 ints
    int* seff = (int*)p;      p += 8;          // 4 ints
    unsigned short* AO = Xb;  // alias: X dead after proj_gemm

    mask_scan<<<dim3(4), 256, 0, stream>>>(mask, kidx, seff);
    ingest<<<dim3(2048), 256, 0, stream>>>(X, Xb, (int)(NE / 4));
    ingest<<<dim3(512), 256, 0, stream>>>(Wq, Wqb, (int)(WE / 4));
    ingest<<<dim3(512), 256, 0, stream>>>(Wk, Wkb, (int)(WE / 4));
    ingest<<<dim3(512), 256, 0, stream>>>(Wv, Wvb, (int)(WE / 4));
    ingest<<<dim3(512), 256, 0, stream>>>(Wr, Wrb, (int)(WE / 4));

    proj_gemm<<<dim3(68, 8, 4), 256, 0, stream>>>(Xb, Wqb, Wkb, Wvb, Wrb,
                                                  Qb, Kb, Vb, Rb, kidx, seff);
    attn_fwd<<<dim3(1024), 512, 0, stream>>>(Qb, Kb, Vb, seff, AO);
    ln_ep<<<dim3(8192), 256, 0, stream>>>(AO, Rb, Gm, Bt, out);
}

// Round 29
// 171.501 us; speedup vs baseline: 1.4759x; 1.0335x over previous
//
#include <hip/hip_runtime.h>

typedef __attribute__((ext_vector_type(8))) short short8;     // 8 bf16 — MFMA A/B frag
typedef __attribute__((ext_vector_type(8))) unsigned short u16x8;
typedef __attribute__((ext_vector_type(4))) float f32x4;      // MFMA C/D frag
typedef __attribute__((ext_vector_type(4))) unsigned short u16x4;
typedef __attribute__((ext_vector_type(4))) float float4v;

#define MFMA(a, b, c) __builtin_amdgcn_mfma_f32_16x16x32_bf16(a, b, c, 0, 0, 0)
#define GLOAD_LDS16(gp, lp) __builtin_amdgcn_global_load_lds( \
    (const __attribute__((address_space(1))) void*)(gp),      \
    (__attribute__((address_space(3))) void*)(lp), 16, 0, 0)

__device__ __forceinline__ float bf2f(unsigned short u) {
    union { unsigned int i; float f; } v; v.i = ((unsigned int)u) << 16; return v.f;
}
__device__ __forceinline__ unsigned short f2bf(float f) {
    union { float f; unsigned int i; } v; v.f = f;
    unsigned int r = (v.i + 0x7FFFu + ((v.i >> 16) & 1u)) >> 16;
    return (unsigned short)r;
}
// cheap round-half-up bf16 (P tile only)
__device__ __forceinline__ unsigned short f2bfr(float f) {
    union { float f; unsigned int i; } v; v.f = f;
    return (unsigned short)((v.i + 0x8000u) >> 16);
}

// ---- mask compaction (r27-verified, unchanged) ----
__global__ __launch_bounds__(256)
void mask_scan(const int* __restrict__ mask, int* __restrict__ kidx, int* __restrict__ seff)
{
    constexpr int S = 2048;
    const int b = blockIdx.x;
    const int tid = threadIdx.x;
    __shared__ int ps[256];
    const int* m = mask + b * S;
    int loc[8], s = 0;
#pragma unroll
    for (int j = 0; j < 8; ++j) { loc[j] = m[tid * 8 + j]; s += loc[j]; }
#pragma unroll
    for (int j = 0; j < 8; ++j) kidx[b * S + tid * 8 + j] = b * S;   // safe default
    ps[tid] = s;
    __syncthreads();
    for (int off = 1; off < 256; off <<= 1) {
        int v = (tid >= off) ? ps[tid - off] : 0;
        __syncthreads();
        ps[tid] += v;
        __syncthreads();
    }
    int run = (tid > 0) ? ps[tid - 1] : 0;
#pragma unroll
    for (int j = 0; j < 8; ++j) {
        if (loc[j]) kidx[b * S + run] = b * S + tid * 8 + j;
        run += loc[j];
    }
    if (tid == 255) seff[b] = ps[255];
}

// ---- fused fp32->bf16 ingest: X + Wq + Wk + Wv + Wr in ONE dispatch ----
// dst buffers are contiguous: Xb | Wqb | Wkb | Wvb | Wrb
__global__ __launch_bounds__(256)
void ingest_all(const float* __restrict__ X,
                const float* __restrict__ Wq, const float* __restrict__ Wk,
                const float* __restrict__ Wv, const float* __restrict__ Wr,
                unsigned short* __restrict__ dst)
{
    constexpr int X4 = 2097152;          // NE/4
    constexpr int T4 = X4 + 4 * 262144;  // + 4*WE/4
    const int stride = gridDim.x * blockDim.x;
    for (int i = blockIdx.x * blockDim.x + threadIdx.x; i < T4; i += stride) {
        const float* src;
        int off;
        if (i < X4) { src = X; off = i; }
        else {
            int jj = i - X4;
            int ws = jj >> 18;
            off = jj & 0x3FFFF;
            src = (ws == 0) ? Wq : (ws == 1) ? Wk : (ws == 2) ? Wv : Wr;
        }
        float4v v = ((const float4v*)src)[off];
        u16x4 o;
#pragma unroll
        for (int j = 0; j < 4; ++j) o[j] = f2bf(v[j]);
        ((u16x4*)dst)[i] = o;
    }
}

// ---- Projection GEMM: m97 core + XCD-colocated 1D grid + LDS-bounce coalesced stores ----
// bid decode: j=bid&7, t=bid>>3, x=(t>>5)*8+j (A-row-tile), c=t&31, wsel=c>>3, coltile=c&7.
// All 32 blocks sharing A-panel x are == j (mod 8) -> same XCD -> X panel L2-resident.
__global__ __launch_bounds__(256)
void proj_gemm(const unsigned short* __restrict__ X,
               const unsigned short* __restrict__ Wq, const unsigned short* __restrict__ Wk,
               const unsigned short* __restrict__ Wv, const unsigned short* __restrict__ Wr,
               unsigned short* __restrict__ Qo, unsigned short* __restrict__ Ko,
               unsigned short* __restrict__ Vo, unsigned short* __restrict__ Ro,
               const int* __restrict__ kidx, const int* __restrict__ seff)
{
    constexpr int Kd = 1024, N = 1024;
    __shared__ unsigned short As[128 * 32];
    __shared__ unsigned short Bs[128 * 32];
    __shared__ unsigned short Ct[128 * 136];   // padded bounce tile (16B-aligned rows)
    const int tid = threadIdx.x;
    const int wid = tid >> 6, lane = tid & 63;
    const int g = lane >> 4, lr = lane & 15;
    const int bid = blockIdx.x;
    const int jx = bid & 7, t = bid >> 3;
    const int x = (t >> 5) * 8 + jx;
    const int c = t & 31;
    const int wsel = c >> 3;
    const int coltile = c & 7;
    const bool compact = (wsel == 1) || (wsel == 2);
    int rowBase;
    if (compact) {
        if (x >= 68) return;
        int b = x / 17, xt = x - b * 17;
        if (xt * 128 >= seff[b]) return;
        rowBase = b * 2048 + xt * 128;
    } else {
        if (x >= 64) return;
        rowBase = x * 128;
    }
    const unsigned short* W = (wsel == 0) ? Wq : (wsel == 1) ? Wk : (wsel == 2) ? Wv : Wr;
    unsigned short* O = (wsel == 0) ? Qo : (wsel == 1) ? Ko : (wsel == 2) ? Vo : Ro;
    const int colBase = coltile * 128;
    const int wm = wid >> 1, wn = wid & 1;

    f32x4 acc[4][4] = {};

    const int r0 = tid >> 2;
    const int c0 = (tid & 3) * 8;
    const int sA0 = compact ? kidx[rowBase + r0] : rowBase + r0;
    const int sA1 = compact ? kidx[rowBase + 64 + r0] : rowBase + 64 + r0;
    const unsigned short* ga0 = X + (size_t)sA0 * Kd + c0;
    const unsigned short* ga1 = X + (size_t)sA1 * Kd + c0;
    const unsigned short* gb0 = W + (size_t)(colBase + r0) * Kd + c0;
    const unsigned short* gb1 = W + (size_t)(colBase + 64 + r0) * Kd + c0;

    for (int kt = 0; kt < Kd; kt += 32) {
        if (kt) __syncthreads();
        GLOAD_LDS16(ga0 + kt, As + (size_t)tid * 8);
        GLOAD_LDS16(ga1 + kt, As + 2048 + (size_t)tid * 8);
        GLOAD_LDS16(gb0 + kt, Bs + (size_t)tid * 8);
        GLOAD_LDS16(gb1 + kt, Bs + 2048 + (size_t)tid * 8);
        asm volatile("s_waitcnt vmcnt(0)" ::: "memory");
        __syncthreads();
        short8 a[4], b[4];
#pragma unroll
        for (int mt = 0; mt < 4; ++mt)
            a[mt] = *reinterpret_cast<const short8*>(&As[(wm * 64 + mt * 16 + lr) * 32 + g * 8]);
#pragma unroll
        for (int nt = 0; nt < 4; ++nt)
            b[nt] = *reinterpret_cast<const short8*>(&Bs[(wn * 64 + nt * 16 + lr) * 32 + g * 8]);
#pragma unroll
        for (int mt = 0; mt < 4; ++mt)
#pragma unroll
            for (int nt = 0; nt < 4; ++nt)
                acc[mt][nt] = MFMA(a[mt], b[nt], acc[mt][nt]);
    }
    // epilogue: C-frag -> LDS bounce -> coalesced u16x8 global stores
#pragma unroll
    for (int mt = 0; mt < 4; ++mt)
#pragma unroll
        for (int nt = 0; nt < 4; ++nt)
#pragma unroll
            for (int r = 0; r < 4; ++r)
                Ct[(wm * 64 + mt * 16 + g * 4 + r) * 136 + wn * 64 + nt * 16 + lr] =
                    f2bf(acc[mt][nt][r]);
    __syncthreads();
#pragma unroll
    for (int pp = 0; pp < 8; ++pp) {
        int row = pp * 16 + (tid >> 4);
        int col = (tid & 15) * 8;
        u16x8 v8 = *reinterpret_cast<const u16x8*>(&Ct[row * 136 + col]);
        *reinterpret_cast<u16x8*>(&O[(size_t)(rowBase + row) * N + colBase + col]) = v8;
    }
}

// ---- MFMA flash attention over COMPACTED K/V (r27-verified, unchanged) ----
__global__ __launch_bounds__(512)
void attn_fwd(const unsigned short* __restrict__ Q, const unsigned short* __restrict__ Kb,
              const unsigned short* __restrict__ Vb, const int* __restrict__ seff,
              unsigned short* __restrict__ AO)
{
    constexpr int S = 2048, C = 1024, Dh = 64;
    constexpr int PST = 64;
    constexpr float SCL = 0.125f * 1.44269504f;
    constexpr float FM  = 16.0f;
    constexpr float MSK = -1.0e30f;
    __shared__ unsigned short Kt[2][64 * 64];
    __shared__ unsigned short Vt[2][64 * 64];
    __shared__ unsigned short Pt[8][16 * PST];
    const int tid = threadIdx.x;
    const int w = tid >> 6, lane = tid & 63;
    const int g = lane >> 4, lr = lane & 15;
    const int lin = blockIdx.x;
    const int hb = lin & 63, qt = lin >> 6;
    const int h = hb >> 2, b = hb & 3;
    const int qbase = qt * 128;
    const int qrow = qbase + w * 16 + lr;

    const int Sb = seff[b];
    const int ntiles = (Sb + 63) >> 6;

    const unsigned short* qptr = Q + (size_t)(b * S + qrow) * C + h * Dh;
    short8 qf[2];
    qf[0] = *reinterpret_cast<const short8*>(qptr + g * 8);
    qf[1] = *reinterpret_cast<const short8*>(qptr + 32 + g * 8);

    short8 ones;
#pragma unroll
    for (int j = 0; j < 8; ++j) ones[j] = (short)0x3F80;

    f32x4 o[4] = {};
    f32x4 lacc = {};

    const unsigned short* kg = Kb + (size_t)(b * S) * C + h * Dh;
    const unsigned short* vg = Vb + (size_t)(b * S) * C + h * Dh;

    const int kk0 = tid >> 3;
    const int kd0 = ((tid & 7) ^ (kk0 & 7)) * 8;
    const int vkey = tid >> 3;
    const int vsd = (tid & 7) * 8;

    short8 vv;
    GLOAD_LDS16(kg + (size_t)kk0 * C + kd0, &Kt[0][(size_t)tid * 8]);
    vv = *reinterpret_cast<const short8*>(vg + (size_t)vkey * C + vsd);
    asm volatile("s_waitcnt vmcnt(0)" ::: "memory");
    {
        const unsigned short* bb = (const unsigned short*)&vv;
#pragma unroll
        for (int j = 0; j < 8; ++j) {
            int d = vsd + j;
            int sw = (d & 7) ^ ((d >> 3) & 7);
            Vt[0][d * 64 + ((((vkey >> 3) ^ sw) << 3) | (vkey & 7))] = bb[j];
        }
    }
    __syncthreads();

    int cur = 0;
    for (int tt = 0; tt < ntiles; ++tt) {
        const int t = tt * 64;
        const bool hasNext = (tt + 1) < ntiles;
        if (hasNext) {
            const int tn = t + 64;
            GLOAD_LDS16(kg + (size_t)(tn + kk0) * C + kd0, &Kt[cur ^ 1][(size_t)tid * 8]);
            vv = *reinterpret_cast<const short8*>(vg + (size_t)(tn + vkey) * C + vsd);
        }
        f32x4 s[4];
        __builtin_amdgcn_s_setprio(1);
#pragma unroll
        for (int nt = 0; nt < 4; ++nt) {
            int key = nt * 16 + lr;
            f32x4 a = {};
#pragma unroll
            for (int c = 0; c < 2; ++c) {
                int dd = c * 32 + g * 8;
                short8 kf = *reinterpret_cast<const short8*>(
                    &Kt[cur][key * 64 + (((dd >> 3) ^ (key & 7)) << 3)]);
                a = MFMA(qf[c], kf, a);
            }
            s[nt] = a;
        }
        __builtin_amdgcn_s_setprio(0);
        float madd[4];
#pragma unroll
        for (int nt = 0; nt < 4; ++nt)
            madd[nt] = ((t + nt * 16 + lr) < Sb) ? -FM : MSK;
        unsigned short* Pw = Pt[w];
#pragma unroll
        for (int nt = 0; nt < 4; ++nt) {
            int k = nt * 16 + lr;
#pragma unroll
            for (int r = 0; r < 4; ++r) {
                float p = __builtin_amdgcn_exp2f(s[nt][r] * SCL + madd[nt]);
                int row = g * 4 + r;
                Pw[row * PST + ((((k >> 3) ^ (row & 7)) << 3) | (k & 7))] = f2bfr(p);
            }
        }
        asm volatile("s_waitcnt lgkmcnt(0)" ::: "memory");
        __builtin_amdgcn_sched_barrier(0);
        short8 pf[2];
#pragma unroll
        for (int hh = 0; hh < 2; ++hh) {
            int kk = hh * 32 + g * 8;
            pf[hh] = *reinterpret_cast<const short8*>(
                &Pw[lr * PST + (((kk >> 3) ^ (lr & 7)) << 3)]);
        }
        __builtin_amdgcn_s_setprio(1);
        lacc = MFMA(pf[0], ones, lacc);
        lacc = MFMA(pf[1], ones, lacc);
#pragma unroll
        for (int dt = 0; dt < 4; ++dt) {
            int d = dt * 16 + lr;
#pragma unroll
            for (int hh = 0; hh < 2; ++hh) {
                int kk = hh * 32 + g * 8;
                short8 vf = *reinterpret_cast<const short8*>(
                    &Vt[cur][d * 64 + ((((kk >> 3) ^ (d & 7) ^ ((d >> 3) & 7)) << 3))]);
                o[dt] = MFMA(pf[hh], vf, o[dt]);
            }
        }
        __builtin_amdgcn_s_setprio(0);
        if (hasNext) {
            asm volatile("s_waitcnt vmcnt(0)" ::: "memory");
            const unsigned short* bb = (const unsigned short*)&vv;
            unsigned short* Vn = Vt[cur ^ 1];
#pragma unroll
            for (int j = 0; j < 8; ++j) {
                int d = vsd + j;
                int sw = (d & 7) ^ ((d >> 3) & 7);
                Vn[d * 64 + ((((vkey >> 3) ^ sw) << 3) | (vkey & 7))] = bb[j];
            }
        }
        __syncthreads();
        cur ^= 1;
    }
#pragma unroll
    for (int dt = 0; dt < 4; ++dt)
#pragma unroll
        for (int r = 0; r < 4; ++r) {
            int row = qbase + w * 16 + g * 4 + r;
            int col = h * Dh + dt * 16 + lr;
            AO[(size_t)(b * S + row) * C + col] = f2bf(o[dt][r] / lacc[r]);
        }
}

// ---- Epilogue (r16-verified, unchanged) ----
__global__ __launch_bounds__(256)
void ln_ep(const unsigned short* __restrict__ AO, const unsigned short* __restrict__ R,
           const float* __restrict__ gamma, const float* __restrict__ beta,
           float* __restrict__ out)
{
    constexpr int C = 1024;
    const int row = blockIdx.x;
    const int tid = threadIdx.x;
    __shared__ float s1[256];
    __shared__ float s2[256];

    float v[4]; float sum = 0.f, ss = 0.f;
#pragma unroll
    for (int i = 0; i < 4; ++i) {
        int c = tid * 4 + i;
        float a = bf2f(AO[(size_t)row * C + c]);
        float r = bf2f(R[(size_t)row * C + c]);
        v[i] = fmaxf(0.f, a + r);
        sum += v[i]; ss += v[i] * v[i];
    }
    s1[tid] = sum; s2[tid] = ss;
    __syncthreads();
    for (int st = 128; st > 0; st >>= 1) {
        if (tid < st) { s1[tid] += s1[tid + st]; s2[tid] += s2[tid + st]; }
        __syncthreads();
    }
    float mu = s1[0] * (1.f / C);
    float var = s2[0] * (1.f / C) - mu * mu;
    float rstd = rsqrtf(var + 1e-5f);
    float4v g4 = *reinterpret_cast<const float4v*>(gamma + tid * 4);
    float4v b4 = *reinterpret_cast<const float4v*>(beta + tid * 4);
    float4v ov;
#pragma unroll
    for (int i = 0; i < 4; ++i)
        ov[i] = (v[i] - mu) * rstd * g4[i] + b4[i];
    *reinterpret_cast<float4v*>(out + (size_t)row * C + tid * 4) = ov;
}

extern "C" void kernel_launch(void* const* d_in, const int* in_sizes, int n_in,
                              void* d_out, int out_size, void* d_ws, size_t ws_size,
                              hipStream_t stream)
{
    const float* X = (const float*)d_in[0];
    const int* mask = (const int*)d_in[1];
    const float* Wq = (const float*)d_in[2];
    const float* Wk = (const float*)d_in[3];
    const float* Wv = (const float*)d_in[4];
    const float* Wr = (const float*)d_in[5];
    const float* Gm = (const float*)d_in[6];
    const float* Bt = (const float*)d_in[7];
    float* out = (float*)d_out;

    const size_t NE = (size_t)8192 * 1024;
    const size_t WE = (size_t)1024 * 1024;
    unsigned short* p = (unsigned short*)d_ws;
    unsigned short* Xb = p;   p += NE;
    unsigned short* Wqb = p;  p += WE;
    unsigned short* Wkb = p;  p += WE;
    unsigned short* Wvb = p;  p += WE;
    unsigned short* Wrb = p;  p += WE;
    unsigned short* Qb = p;   p += NE;
    unsigned short* Kb = p;   p += NE;
    unsigned short* Vb = p;   p += NE;
    unsigned short* Rb = p;   p += NE;
    int* kidx = (int*)p;      p += 8192 * 2;
    int* seff = (int*)p;      p += 8;
    unsigned short* AO = Xb;  // alias: X dead after proj_gemm

    mask_scan<<<dim3(4), 256, 0, stream>>>(mask, kidx, seff);
    ingest_all<<<dim3(2048), 256, 0, stream>>>(X, Wq, Wk, Wv, Wr, Xb);

    proj_gemm<<<dim3(2304), 256, 0, stream>>>(Xb, Wqb, Wkb, Wvb, Wrb,
                                              Qb, Kb, Vb, Rb, kidx, seff);
    attn_fwd<<<dim3(1024), 512, 0, stream>>>(Qb, Kb, Vb, seff, AO);
    ln_ep<<<dim3(8192), 256, 0, stream>>>(AO, Rb, Gm, Bt, out);
}